// Round 2
// baseline (2063.110 us; speedup 1.0000x reference)
//
#include <hip/hip_runtime.h>

// Problem constants
#define GM    1024
#define GK    4096
#define GN    50257
#define NPADW 50304         // 393*128 storage rows for W_bf16 (zero-padded) — matches proven ws footprint
#define NTILES 197          // ceil(50257/256): grid covers 50432 cols; B-row addrs clamped to NPADW

typedef __attribute__((ext_vector_type(8))) __bf16 bf16x8;
typedef __attribute__((ext_vector_type(4))) float  f32x4;

// ---- fp32 -> bf16 (round to nearest even) ----
__device__ __forceinline__ short f2bf(float f) {
    unsigned int u = __float_as_uint(f);
    u += 0x7fffu + ((u >> 16) & 1u);
    return (short)(u >> 16);
}

// ---- async global->LDS, 16B per lane ----
__device__ __forceinline__ void gload_lds16(const void* g, void* l) {
    __builtin_amdgcn_global_load_lds(
        (const __attribute__((address_space(1))) void*)g,
        (__attribute__((address_space(3))) void*)l,
        16, 0, 0);
}

// ---- x fp32 [1024][4096] -> bf16, one float4 chunk per thread ----
__global__ __launch_bounds__(256) void cvt_x(const float* __restrict__ s,
                                             short* __restrict__ d) {
    int i = blockIdx.x * 256 + threadIdx.x;           // 1,048,576 chunks exact
    float4 v = ((const float4*)s)[i];
    short4 o;
    o.x = f2bf(v.x); o.y = f2bf(v.y); o.z = f2bf(v.z); o.w = f2bf(v.w);
    ((short4*)d)[i] = o;
}

// ---- W fp32 [50257][4096] -> bf16 [50304][4096], pad rows zeroed ----
__global__ __launch_bounds__(256) void cvt_w(const float* __restrict__ s,
                                             short* __restrict__ d) {
    int i = blockIdx.x * 256 + threadIdx.x;           // 51,511,296 chunks exact
    int row = i >> 10;                                 // 1024 chunks per row
    short4 o;
    if (row < GN) {
        float4 v = ((const float4*)s)[i];
        o.x = f2bf(v.x); o.y = f2bf(v.y); o.z = f2bf(v.z); o.w = f2bf(v.w);
    } else {
        o.x = 0; o.y = 0; o.z = 0; o.w = 0;
    }
    ((short4*)d)[i] = o;
}

// ---- C[1024][50257] = A[1024][4096] * B[50304][4096]^T + bias ----
// 256x256 tile, BK=32, 8 waves (2M x 4N), each wave 8x4 MFMA 16x16x32.
// Proven 2-barrier structure; tile doubled vs 128^2 baseline to halve staged
// traffic (6.29 -> 3.15 GB) since the baseline GEMM was HBM/L3-bound.
__global__ __launch_bounds__(512, 2) void gemm_bt(const __bf16* __restrict__ A,
                                                  const __bf16* __restrict__ B,
                                                  const float* __restrict__ bias,
                                                  float* __restrict__ C) {
    __shared__ __bf16 lA[256 * 32];   // 16 KB
    __shared__ __bf16 lB[256 * 32];   // 16 KB

    const int tid  = threadIdx.x;
    const int wave = tid >> 6;
    const int lane = tid & 63;

    // Bijective XCD swizzle (m204): hardware round-robins XCD = blockIdx%8.
    // Map so each N-panel's 4 M-blocks are contiguous in logical id -> same
    // XCD -> W panel read once into that XCD's L2 and reused 4x.
    const int b = blockIdx.x;                          // 788 blocks
    const int x = b & 7, s = b >> 3;
    const int q = 98, r = 4;                           // 788/8, 788%8
    const int lid = ((x < r) ? x * (q + 1) : r * (q + 1) + (x - r) * q) + s;
    const int m0 = (lid & 3)  << 8;                    // m-tile fast
    const int n0 = (lid >> 2) << 8;

    // staging addresses: one 8 KB round covers 128 rows x 64 B; 2 rounds each
    const int o  = tid << 4;                           // byte within round
    const int r0 = o >> 6;                             // row 0..127
    const int cb = o & 63;                             // col-byte
    const size_t rb = (size_t)GK * 2;                  // 8192 B per row
    // B rows clamped to stored range: clamped rows only feed cols >= 50304
    // (never written); rows 50257..50303 are zeroed pad. Keeps ws footprint
    // identical to the proven baseline.
    const int br0 = min(n0 + r0,       NPADW - 1);
    const int br1 = min(n0 + r0 + 128, NPADW - 1);
    const char* pA0 = (const char*)A + (size_t)(m0 + r0) * rb + cb;
    const char* pA1 = pA0 + 128 * rb;
    const char* pB0 = (const char*)B + (size_t)br0 * rb + cb;
    const char* pB1 = (const char*)B + (size_t)br1 * rb + cb;
    char* lA0 = (char*)lA + wave * 1024;
    char* lA1 = (char*)lA + 8192 + wave * 1024;
    char* lB0 = (char*)lB + wave * 1024;
    char* lB1 = (char*)lB + 8192 + wave * 1024;

    f32x4 acc[8][4] = {};

    const int wm   = wave & 1;                         // M half (128 rows)
    const int wn   = wave >> 1;                        // N quarter (64 cols)
    const int frow = lane & 15;
    const int fk   = (lane >> 4) << 3;
    const int aoff = (wm * 128 + frow) * 32 + fk;
    const int boff = (wn * 64 + frow) * 32 + fk;

    for (int kt = 0; kt < GK / 32; ++kt) {
        __syncthreads();                               // prev tile consumed
        gload_lds16(pA0, lA0);
        gload_lds16(pA1, lA1);
        gload_lds16(pB0, lB0);
        gload_lds16(pB1, lB1);
        pA0 += 64; pA1 += 64; pB0 += 64; pB1 += 64;
        __syncthreads();                               // staging complete

        bf16x8 bF[4];
#pragma unroll
        for (int j = 0; j < 4; ++j)
            bF[j] = *(const bf16x8*)&lB[boff + j * 512];

        // two M-halves: caps live A-frags at 4 (register pressure)
#pragma unroll
        for (int h = 0; h < 2; ++h) {
            bf16x8 aF[4];
#pragma unroll
            for (int i = 0; i < 4; ++i)
                aF[i] = *(const bf16x8*)&lA[aoff + (h * 4 + i) * 512];
#pragma unroll
            for (int i = 0; i < 4; ++i)
#pragma unroll
                for (int j = 0; j < 4; ++j)
                    acc[h * 4 + i][j] = __builtin_amdgcn_mfma_f32_16x16x32_bf16(
                        aF[i], bF[j], acc[h * 4 + i][j], 0, 0, 0);
        }
    }

    // epilogue: D elem (reg r, lane l) -> row = (l>>4)*4 + r, col = l&15
    const int crow = (lane >> 4) << 2;
    const int ccol = lane & 15;
#pragma unroll
    for (int j = 0; j < 4; ++j) {
        const int col = n0 + wn * 64 + j * 16 + ccol;
        if (col < GN) {
            const float bj = bias[col];
#pragma unroll
            for (int i = 0; i < 8; ++i) {
                const int row = m0 + wm * 128 + i * 16 + crow;
                float* cp = C + (size_t)row * GN + col;
#pragma unroll
                for (int r2 = 0; r2 < 4; ++r2)
                    cp[(size_t)r2 * GN] = acc[i][j][r2] + bj;
            }
        }
    }
}

// ---- in-place row softmax over [1024][50257], 2-pass online (m,s) ----
__global__ __launch_bounds__(256) void softmax_rows(float* __restrict__ C) {
    float* row = C + (size_t)blockIdx.x * GN;
    const int tid = threadIdx.x;
    __shared__ float redm[4], reds[4];

    // pass 1: online max + sum-of-exp in one sweep
    float m = -3.0e38f, s = 0.f;
    for (int i = tid; i < GN; i += 256) {
        float v = row[i];
        if (v <= m) {
            s += __expf(v - m);
        } else {
            s = s * __expf(m - v) + 1.0f;
            m = v;
        }
    }
#pragma unroll
    for (int o = 32; o > 0; o >>= 1) {
        float m2 = __shfl_xor(m, o, 64);
        float s2 = __shfl_xor(s, o, 64);
        float M  = fmaxf(m, m2);
        s = s * __expf(m - M) + s2 * __expf(m2 - M);
        m = M;
    }
    if ((tid & 63) == 0) { redm[tid >> 6] = m; reds[tid >> 6] = s; }
    __syncthreads();
    const float M = fmaxf(fmaxf(redm[0], redm[1]), fmaxf(redm[2], redm[3]));
    const float S = reds[0] * __expf(redm[0] - M) + reds[1] * __expf(redm[1] - M)
                  + reds[2] * __expf(redm[2] - M) + reds[3] * __expf(redm[3] - M);
    const float inv = 1.0f / S;

    // pass 2: normalize
    for (int i = tid; i < GN; i += 256) row[i] = __expf(row[i] - M) * inv;
}

extern "C" void kernel_launch(void* const* d_in, const int* in_sizes, int n_in,
                              void* d_out, int out_size, void* d_ws, size_t ws_size,
                              hipStream_t stream) {
    const float* x = (const float*)d_in[0];   // [1024][4096]
    const float* W = (const float*)d_in[1];   // [50257][4096]
    const float* b = (const float*)d_in[2];   // [50257]
    float* out = (float*)d_out;               // [1024][50257]

    // ws layout: x_bf16 (8,388,608 B) | W_bf16 padded to 50304 rows (412,090,368 B)
    // total 420,478,976 B — identical to the proven baseline footprint.
    short* xb = (short*)d_ws;
    short* Wb = (short*)((char*)d_ws + (size_t)GM * GK * 2);

    cvt_x<<<4096, 256, 0, stream>>>(x, xb);                       // 1M chunks
    cvt_w<<<201216, 256, 0, stream>>>(W, Wb);                     // 51.5M chunks
    gemm_bt<<<NTILES * (GM / 256), 512, 0, stream>>>(
        (const __bf16*)xb, (const __bf16*)Wb, b, out);            // 788 blocks
    softmax_rows<<<GM, 256, 0, stream>>>(out);
}